// Round 1
// baseline (933.440 us; speedup 1.0000x reference)
//
#include <hip/hip_runtime.h>

#define N_NODES 50000
#define L_LAYERS 2
#define F_IN 128
#define F_OUT 32
#define E_L 800000
#define NEG_SLOPE 0.2f
#define LN (L_LAYERS * N_NODES)   // 100000

// ---------------------------------------------------------------------------
// Kernel A: random-edge degree counts (int atomics). Self-loop + inter-layer
// edge contribute a constant +2 to every node's src and trg counts, folded in
// later as (cnt + 2).
// ---------------------------------------------------------------------------
__global__ __launch_bounds__(256) void deg_kernel(
    const int* __restrict__ e0, const int* __restrict__ e1,
    int* __restrict__ cnt_src, int* __restrict__ cnt_trg) {
    int t = blockIdx.x * blockDim.x + threadIdx.x;
    if (t >= 2 * E_L) return;
    int l = (t >= E_L) ? 1 : 0;
    int e = t - l * E_L;
    const int* ei = l ? e1 : e0;
    int u = ei[e]       + l * N_NODES;
    int v = ei[E_L + e] + l * N_NODES;
    atomicAdd(&cnt_src[u], 1);
    atomicAdd(&cnt_trg[v], 1);
}

// ---------------------------------------------------------------------------
// Kernel B: proj = x @ W_proj^T  (N x 128 @ 128 x 64), scaled by outdeg_inv,
// stored as scaled[(l*N+n)*32 + f] with o = l*32+f.
// W transposed in LDS (Wt[k][o]: consecutive-lane reads, 2-way bank alias =
// free). x tile broadcast-read from LDS.
// ---------------------------------------------------------------------------
__global__ __launch_bounds__(256) void proj_kernel(
    const float* __restrict__ x, const float* __restrict__ Wp,
    const int* __restrict__ cnt_trg, float* __restrict__ scaled) {
    __shared__ float Wt[F_IN][64];    // 32 KB, Wt[k][o] = Wp[o*128+k]
    __shared__ float xt[8][F_IN];     // 4 KB, 8-node tile
    const int t = threadIdx.x;
    for (int i = t; i < 64 * F_IN; i += 256) {
        int o = i / F_IN, k = i % F_IN;
        Wt[k][o] = Wp[i];
    }
    const int lane = t & 63;
    const int wave = t >> 6;
    const int ntiles = N_NODES / 8;   // 6250, exact
    for (int tile = blockIdx.x; tile < ntiles; tile += gridDim.x) {
        const int base = tile * 8;
        __syncthreads();              // also covers initial W-load
        // stage 8 nodes x 128 floats = 256 float4, one per thread (coalesced)
        ((float4*)&xt[0][0])[t] = ((const float4*)(x + (size_t)base * F_IN))[t];
        __syncthreads();
        #pragma unroll
        for (int s = 0; s < 2; ++s) {
            const int nl = wave + 4 * s;
            const int n = base + nl;
            float acc = 0.f;
            #pragma unroll
            for (int k = 0; k < F_IN; k += 4) {
                // x reads: wave-uniform address -> broadcast (b128);
                // W reads: consecutive lanes -> conflict-free
                acc += xt[nl][k + 0] * Wt[k + 0][lane];
                acc += xt[nl][k + 1] * Wt[k + 1][lane];
                acc += xt[nl][k + 2] * Wt[k + 2][lane];
                acc += xt[nl][k + 3] * Wt[k + 3][lane];
            }
            const int l = lane >> 5, f = lane & 31;
            const int v = l * N_NODES + n;
            const float od = 1.0f / sqrtf((float)(cnt_trg[v] + 2));
            scaled[(size_t)v * F_OUT + f] = acc * od;
        }
    }
}

// ---------------------------------------------------------------------------
// Kernel C: scatter-add over the 1.6M random edges.
// Thread handles 4 features (float4 gather + 4 native f32 atomics).
// ---------------------------------------------------------------------------
__global__ __launch_bounds__(256) void agg_kernel(
    const int* __restrict__ e0, const int* __restrict__ e1,
    const float* __restrict__ scaled, float* __restrict__ agg) {
    int t = blockIdx.x * blockDim.x + threadIdx.x;       // up to 12.8M
    if (t >= 2 * E_L * 8) return;
    const int fb = (t & 7) * 4;                          // feature base
    const int eg = t >> 3;                               // global edge id
    const int l  = (eg >= E_L) ? 1 : 0;
    const int e  = eg - l * E_L;
    const int* ei = l ? e1 : e0;
    const int u = ei[e]       + l * N_NODES;
    const int v = ei[E_L + e] + l * N_NODES;
    const float4 val = *(const float4*)(scaled + (size_t)u * F_OUT + fb);
    float* dst = agg + (size_t)v * F_OUT + fb;
    unsafeAtomicAdd(dst + 0, val.x);
    unsafeAtomicAdd(dst + 1, val.y);
    unsafeAtomicAdd(dst + 2, val.z);
    unsafeAtomicAdd(dst + 3, val.w);
}

// ---------------------------------------------------------------------------
// Kernel D: tot = agg_random + scaled[v] (self-loop) + scaled[partner] (inter);
// h = leakyrelu(indeg_inv*tot + bias); out = h @ W_merge^T  (64 -> 32).
// ---------------------------------------------------------------------------
__global__ __launch_bounds__(256) void merge_kernel(
    const float* __restrict__ agg, const float* __restrict__ scaled,
    const int* __restrict__ cnt_src, const float* __restrict__ Wm,
    const float* __restrict__ bias, float* __restrict__ out) {
    __shared__ float Wt[64][32];      // 8 KB, Wt[k][o] = Wm[o*64+k]
    __shared__ float h[8][64];
    __shared__ float bs[64];
    const int t = threadIdx.x;
    for (int i = t; i < 32 * 64; i += 256) {
        int o = i >> 6, k = i & 63;
        Wt[k][o] = Wm[i];
    }
    if (t < 64) bs[t] = bias[t];      // bias flat (2,32) matches k = l*32+f
    const int ntiles = N_NODES / 8;   // 6250, exact
    for (int tile = blockIdx.x; tile < ntiles; tile += gridDim.x) {
        const int base = tile * 8;
        __syncthreads();
        // phase 1: 8 nodes x 64 features, 2 per thread
        #pragma unroll
        for (int jj = 0; jj < 2; ++jj) {
            const int j = t + jj * 256;
            const int nl = j >> 6, k = j & 63;
            const int l = k >> 5, f = k & 31;
            const int n = base + nl;
            const int v  = l * N_NODES + n;
            const int vp = (1 - l) * N_NODES + n;
            float tot = agg[(size_t)v * F_OUT + f]
                      + scaled[(size_t)v * F_OUT + f]
                      + scaled[(size_t)vp * F_OUT + f];
            const float id = 1.0f / sqrtf((float)(cnt_src[v] + 2));
            float val = id * tot + bs[k];
            h[nl][k] = (val >= 0.f) ? val : NEG_SLOPE * val;
        }
        __syncthreads();
        // phase 2: 8 nodes x 32 outputs, 1 per thread
        {
            const int nl = t >> 5, o = t & 31;
            float acc = 0.f;
            #pragma unroll
            for (int k = 0; k < 64; ++k)
                acc += h[nl][k] * Wt[k][o];   // h: broadcast; Wt: conflict-free
            out[(size_t)(base + nl) * F_OUT + o] = acc;
        }
    }
}

// ---------------------------------------------------------------------------
extern "C" void kernel_launch(void* const* d_in, const int* in_sizes, int n_in,
                              void* d_out, int out_size, void* d_ws, size_t ws_size,
                              hipStream_t stream) {
    const float* x    = (const float*)d_in[0];
    const int*   e0   = (const int*)d_in[1];
    const int*   e1   = (const int*)d_in[2];
    const float* Wp   = (const float*)d_in[3];
    const float* Wm   = (const float*)d_in[4];
    const float* bias = (const float*)d_in[5];
    float* out = (float*)d_out;

    // workspace layout
    float* scaled  = (float*)d_ws;              // LN*32 floats = 12.8 MB
    float* agg     = scaled + (size_t)LN * F_OUT;  // 12.8 MB
    int*   cnt_src = (int*)(agg + (size_t)LN * F_OUT);  // 400 KB
    int*   cnt_trg = cnt_src + LN;                      // 400 KB

    hipMemsetAsync(agg, 0, (size_t)LN * F_OUT * sizeof(float), stream);
    hipMemsetAsync(cnt_src, 0, (size_t)2 * LN * sizeof(int), stream);

    deg_kernel<<<(2 * E_L + 255) / 256, 256, 0, stream>>>(e0, e1, cnt_src, cnt_trg);
    proj_kernel<<<1024, 256, 0, stream>>>(x, Wp, cnt_trg, scaled);
    agg_kernel<<<(2 * E_L * 8) / 256, 256, 0, stream>>>(e0, e1, scaled, agg);
    merge_kernel<<<1024, 256, 0, stream>>>(agg, scaled, cnt_src, Wm, bias, out);
}

// Round 2
// 413.422 us; speedup vs baseline: 2.2578x; 2.2578x over previous
//
#include <hip/hip_runtime.h>

#define N_NODES 50000
#define L_LAYERS 2
#define F_IN 128
#define F_OUT 32
#define E_L 800000
#define NEG_SLOPE 0.2f
#define LN (L_LAYERS * N_NODES)         // 100000
#define SCAN_CHUNK 512
#define NB_SCAN ((LN + SCAN_CHUNK - 1) / SCAN_CHUNK)   // 196

// ---------------------------------------------------------------------------
// A: random-edge degree counts (int atomics). Self-loop + inter-layer edge
// add a constant +2 per node, folded analytically later as (cnt + 2).
// ---------------------------------------------------------------------------
__global__ __launch_bounds__(256) void deg_kernel(
    const int* __restrict__ e0, const int* __restrict__ e1,
    int* __restrict__ cnt_src, int* __restrict__ cnt_trg) {
    int t = blockIdx.x * blockDim.x + threadIdx.x;
    if (t >= 2 * E_L) return;
    int l = (t >= E_L) ? 1 : 0;
    int e = t - l * E_L;
    const int* ei = l ? e1 : e0;
    int u = ei[e]       + l * N_NODES;
    int v = ei[E_L + e] + l * N_NODES;
    atomicAdd(&cnt_src[u], 1);
    atomicAdd(&cnt_trg[v], 1);
}

// ---------------------------------------------------------------------------
// B: 3-pass exclusive scan of cnt_trg -> rowptr (and cursor copy).
// ---------------------------------------------------------------------------
__global__ __launch_bounds__(256) void scan_pass1(
    const int* __restrict__ cnt, int* __restrict__ bsum) {
    __shared__ int s[256];
    const int b = blockIdx.x, t = threadIdx.x;
    const int base = b * SCAN_CHUNK + 2 * t;
    int v0 = (base     < LN) ? cnt[base]     : 0;
    int v1 = (base + 1 < LN) ? cnt[base + 1] : 0;
    s[t] = v0 + v1;
    __syncthreads();
    for (int off = 128; off > 0; off >>= 1) {
        if (t < off) s[t] += s[t + off];
        __syncthreads();
    }
    if (t == 0) bsum[b] = s[0];
}

__global__ __launch_bounds__(256) void scan_pass2(
    const int* __restrict__ bsum, int* __restrict__ boff) {
    __shared__ int s[256];
    const int t = threadIdx.x;
    int v = (t < NB_SCAN) ? bsum[t] : 0;
    s[t] = v;
    __syncthreads();
    for (int off = 1; off < 256; off <<= 1) {   // inclusive Hillis-Steele
        int add = (t >= off) ? s[t - off] : 0;
        __syncthreads();
        s[t] += add;
        __syncthreads();
    }
    if (t < NB_SCAN) boff[t] = s[t] - v;        // exclusive
}

__global__ __launch_bounds__(256) void scan_pass3(
    const int* __restrict__ cnt, const int* __restrict__ boff,
    int* __restrict__ rowptr, int* __restrict__ cursor) {
    __shared__ int ts[256];
    const int b = blockIdx.x, t = threadIdx.x;
    const int base = b * SCAN_CHUNK + 2 * t;
    int v0 = (base     < LN) ? cnt[base]     : 0;
    int v1 = (base + 1 < LN) ? cnt[base + 1] : 0;
    int sum = v0 + v1;
    ts[t] = sum;
    __syncthreads();
    for (int off = 1; off < 256; off <<= 1) {
        int add = (t >= off) ? ts[t - off] : 0;
        __syncthreads();
        ts[t] += add;
        __syncthreads();
    }
    int excl = ts[t] - sum + boff[b];
    if (base     < LN) { rowptr[base]     = excl;      cursor[base]     = excl;      }
    if (base + 1 < LN) { rowptr[base + 1] = excl + v0; cursor[base + 1] = excl + v0; }
}

// ---------------------------------------------------------------------------
// C: CSR fill — slot = cursor[v]++ (int atomic), col[slot] = u.
// ---------------------------------------------------------------------------
__global__ __launch_bounds__(256) void fill_kernel(
    const int* __restrict__ e0, const int* __restrict__ e1,
    int* __restrict__ cursor, int* __restrict__ col) {
    int t = blockIdx.x * blockDim.x + threadIdx.x;
    if (t >= 2 * E_L) return;
    int l = (t >= E_L) ? 1 : 0;
    int e = t - l * E_L;
    const int* ei = l ? e1 : e0;
    int u = ei[e]       + l * N_NODES;
    int v = ei[E_L + e] + l * N_NODES;
    int slot = atomicAdd(&cursor[v], 1);
    col[slot] = u;
}

// ---------------------------------------------------------------------------
// D: proj = (x @ W_proj^T) * outdeg_inv, stored scaled[(l*N+n)*32+f].
// W in LDS row-major padded to 132 (float4 reads -> 2-way alias = free);
// x tile broadcast-read as float4.
// ---------------------------------------------------------------------------
__global__ __launch_bounds__(256) void proj_kernel(
    const float* __restrict__ x, const float* __restrict__ Wp,
    const int* __restrict__ cnt_trg, float* __restrict__ scaled) {
    __shared__ float Wtt[64][132];   // Wtt[o][k] = Wp[o*128+k]
    __shared__ float xt[8][F_IN];
    const int t = threadIdx.x;
    for (int i = t; i < 64 * F_IN; i += 256) {
        int o = i >> 7, k = i & 127;
        Wtt[o][k] = Wp[i];
    }
    const int lane = t & 63, w = t >> 6;
    const int ntiles = N_NODES / 8;          // 6250, exact
    for (int tile = blockIdx.x; tile < ntiles; tile += gridDim.x) {
        const int base = tile * 8;
        __syncthreads();                     // also covers initial W-load
        ((float4*)&xt[0][0])[t] = ((const float4*)(x + (size_t)base * F_IN))[t];
        __syncthreads();
        const int n0 = w, n1 = w + 4;
        float acc0 = 0.f, acc1 = 0.f;
        #pragma unroll
        for (int k = 0; k < F_IN; k += 4) {
            float4 wv = *(const float4*)&Wtt[lane][k];
            float4 x0 = *(const float4*)&xt[n0][k];
            float4 x1 = *(const float4*)&xt[n1][k];
            acc0 += wv.x * x0.x + wv.y * x0.y + wv.z * x0.z + wv.w * x0.w;
            acc1 += wv.x * x1.x + wv.y * x1.y + wv.z * x1.z + wv.w * x1.w;
        }
        const int l = lane >> 5, f = lane & 31;
        {
            const int v = l * N_NODES + base + n0;
            const float od = 1.0f / sqrtf((float)(cnt_trg[v] + 2));
            scaled[(size_t)v * F_OUT + f] = acc0 * od;
        }
        {
            const int v = l * N_NODES + base + n1;
            const float od = 1.0f / sqrtf((float)(cnt_trg[v] + 2));
            scaled[(size_t)v * F_OUT + f] = acc1 * od;
        }
    }
}

// ---------------------------------------------------------------------------
// E: fused gather-aggregate + self/inter fold + leaky + merge GEMM (64->32).
// 16 nodes/block; 8 lanes per (node,layer) row; no atomics.
// ---------------------------------------------------------------------------
__global__ __launch_bounds__(256) void gathermerge_kernel(
    const int* __restrict__ rowptr, const int* __restrict__ cnt_trg,
    const int* __restrict__ col, const float* __restrict__ scaled,
    const int* __restrict__ cnt_src, const float* __restrict__ Wm,
    const float* __restrict__ bias, float* __restrict__ out) {
    __shared__ float Wt[64][32];   // Wt[k][o] = Wm[o*64+k]
    __shared__ float h[16][64];
    __shared__ float bs[64];
    const int t = threadIdx.x;
    for (int i = t; i < 32 * 64; i += 256) {
        int o = i & 31, k = i >> 5;
        Wt[k][o] = Wm[o * 64 + k];
    }
    if (t < 64) bs[t] = bias[t];              // bias flat (2,32), k = l*32+f
    const int g  = t >> 3;                    // 0..31: (node,layer) group
    const int fb = (t & 7) * 4;               // feature base (float4)
    const int nl = g & 15, l = g >> 4;
    const int ntiles = N_NODES / 16;          // 3125, exact
    for (int tile = blockIdx.x; tile < ntiles; tile += gridDim.x) {
        const int n  = tile * 16 + nl;
        const int v  = l * N_NODES + n;
        const int vp = (1 - l) * N_NODES + n;
        const int start = rowptr[v];
        const int deg   = cnt_trg[v];
        float4 acc = make_float4(0.f, 0.f, 0.f, 0.f);
        for (int i = 0; i < deg; ++i) {
            const int u = col[start + i];
            const float4 gv = *(const float4*)(scaled + (size_t)u * F_OUT + fb);
            acc.x += gv.x; acc.y += gv.y; acc.z += gv.z; acc.w += gv.w;
        }
        const float4 sv = *(const float4*)(scaled + (size_t)v  * F_OUT + fb);
        const float4 pv = *(const float4*)(scaled + (size_t)vp * F_OUT + fb);
        const float id = 1.0f / sqrtf((float)(cnt_src[v] + 2));
        __syncthreads();                      // h reuse guard from prev tile
        #pragma unroll
        for (int j = 0; j < 4; ++j) {
            float tot = ((&acc.x)[j] + (&sv.x)[j] + (&pv.x)[j]) * id
                      + bs[l * 32 + fb + j];
            h[nl][l * 32 + fb + j] = (tot >= 0.f) ? tot : NEG_SLOPE * tot;
        }
        __syncthreads();
        #pragma unroll
        for (int jj = 0; jj < 2; ++jj) {
            const int idx = t + jj * 256;
            const int n2 = idx >> 5, o = idx & 31;
            float a = 0.f;
            #pragma unroll
            for (int k = 0; k < 64; ++k)
                a += h[n2][k] * Wt[k][o];     // h: half-wave broadcast; Wt: cf
            out[(size_t)(tile * 16 + n2) * F_OUT + o] = a;
        }
    }
}

// ---------------------------------------------------------------------------
extern "C" void kernel_launch(void* const* d_in, const int* in_sizes, int n_in,
                              void* d_out, int out_size, void* d_ws, size_t ws_size,
                              hipStream_t stream) {
    const float* x    = (const float*)d_in[0];
    const int*   e0   = (const int*)d_in[1];
    const int*   e1   = (const int*)d_in[2];
    const float* Wp   = (const float*)d_in[3];
    const float* Wm   = (const float*)d_in[4];
    const float* bias = (const float*)d_in[5];
    float* out = (float*)d_out;

    // workspace layout (~20.8 MB)
    float* scaled  = (float*)d_ws;                       // LN*32 f = 12.8 MB
    int*   cnt_src = (int*)(scaled + (size_t)LN * F_OUT);// 400 KB
    int*   cnt_trg = cnt_src + LN;                       // 400 KB
    int*   rowptr  = cnt_trg + LN;                       // 400 KB
    int*   cursor  = rowptr + LN;                        // 400 KB
    int*   bsum    = cursor + LN;                        // NB_SCAN ints
    int*   boff    = bsum + NB_SCAN;                     // NB_SCAN ints
    int*   col     = boff + NB_SCAN;                     // 2*E_L = 6.4 MB

    hipMemsetAsync(cnt_src, 0, (size_t)2 * LN * sizeof(int), stream);

    deg_kernel <<<(2 * E_L + 255) / 256, 256, 0, stream>>>(e0, e1, cnt_src, cnt_trg);
    scan_pass1 <<<NB_SCAN, 256, 0, stream>>>(cnt_trg, bsum);
    scan_pass2 <<<1,       256, 0, stream>>>(bsum, boff);
    scan_pass3 <<<NB_SCAN, 256, 0, stream>>>(cnt_trg, boff, rowptr, cursor);
    fill_kernel<<<(2 * E_L + 255) / 256, 256, 0, stream>>>(e0, e1, cursor, col);
    proj_kernel<<<1024, 256, 0, stream>>>(x, Wp, cnt_trg, scaled);
    gathermerge_kernel<<<2048, 256, 0, stream>>>(rowptr, cnt_trg, col, scaled,
                                                 cnt_src, Wm, bias, out);
}